// Round 10
// baseline (117.339 us; speedup 1.0000x reference)
//
#include <hip/hip_runtime.h>
#include <hip/hip_bf16.h>
#include <math.h>

// x: (B=16, S=512, T=64, F=256) fp32.  rows = B*S = 8192, tile = T*F = 16384 floats.
// out[row][f] = sum_t softmax_t( sum_f' x[row][t][f'] * wq[row][f'] ) * x[row][t][f]
// wq[row][f]  = sum_d W[f][d] * x[row][63][d]

#define TT 64
#define FF 256
#define KC 64   // K-chunk in wq GEMM
#define BM 32   // row-tile (halved from 64: 1024 blocks -> 4/CU -> 16 waves/CU)
#define QPAD 34 // qs row pitch: even (b64-aligned float2), 34*4%32banks -> 4-way max on writes
#define WPAD 68 // ws row pitch: multiple of 4 (b128-aligned float4)

typedef float v4f __attribute__((ext_vector_type(4)));

__device__ __forceinline__ float4 ntload4(const float* p) {
    v4f t = __builtin_nontemporal_load(reinterpret_cast<const v4f*>(p));
    float4 r; r.x = t.x; r.y = t.y; r.z = t.z; r.w = t.w;
    return r;
}

// ---------------- kernel 1: wq = q @ W^T register-tiled GEMM, 32x64 tile ----------------
// grid = (8192/32) * (256/64) = 1024 blocks, 256 threads, each thread 2 rows x 4 f.
__global__ __launch_bounds__(256) void wq_gemm(const float* __restrict__ x,
                                               const float* __restrict__ W,
                                               float* __restrict__ wq) {
    __shared__ float qs[KC][QPAD];   // qs[k][r]  r = row within tile (0..31)
    __shared__ float ws[KC][WPAD];   // ws[k][f]  f = feature within tile (0..63)

    const int tid = threadIdx.x;
    const int r0 = (blockIdx.x >> 2) * BM;
    const int f0 = (blockIdx.x & 3) * 64;

    const int tf = tid & 15;        // f-group: f0 + 4*tf .. +3
    const int tr = tid >> 4;        // row-group: rows 2*tr, 2*tr+1

    float4 acc[2];
    acc[0] = make_float4(0.f, 0.f, 0.f, 0.f);
    acc[1] = make_float4(0.f, 0.f, 0.f, 0.f);

    for (int k0 = 0; k0 < FF; k0 += KC) {
        __syncthreads();   // protect LDS from previous chunk's readers
        // stage q: 32 rows x 16 float4 = 512 -> 2 per thread
#pragma unroll
        for (int p = 0; p < 2; ++p) {
            int idx = tid + 256 * p;
            int r  = idx >> 4;      // 0..31
            int sc = idx & 15;
            float4 v = *reinterpret_cast<const float4*>(
                x + (size_t)(r0 + r) * (TT * FF) + (size_t)(TT - 1) * FF + k0 + 4 * sc);
            qs[4 * sc + 0][r] = v.x;
            qs[4 * sc + 1][r] = v.y;
            qs[4 * sc + 2][r] = v.z;
            qs[4 * sc + 3][r] = v.w;
        }
        // stage W: 64 f-rows x 16 float4 = 1024 -> 4 per thread
#pragma unroll
        for (int p = 0; p < 4; ++p) {
            int idx = tid + 256 * p;
            int fr = idx >> 4;      // 0..63
            int sc = idx & 15;
            float4 u = *reinterpret_cast<const float4*>(
                W + (size_t)(f0 + fr) * FF + k0 + 4 * sc);
            ws[4 * sc + 0][fr] = u.x;
            ws[4 * sc + 1][fr] = u.y;
            ws[4 * sc + 2][fr] = u.z;
            ws[4 * sc + 3][fr] = u.w;
        }
        __syncthreads();

#pragma unroll
        for (int k = 0; k < KC; ++k) {
            float2 qv = *reinterpret_cast<const float2*>(&qs[k][2 * tr]);
            float4 wv = *reinterpret_cast<const float4*>(&ws[k][4 * tf]);
            acc[0].x = fmaf(qv.x, wv.x, acc[0].x);
            acc[0].y = fmaf(qv.x, wv.y, acc[0].y);
            acc[0].z = fmaf(qv.x, wv.z, acc[0].z);
            acc[0].w = fmaf(qv.x, wv.w, acc[0].w);
            acc[1].x = fmaf(qv.y, wv.x, acc[1].x);
            acc[1].y = fmaf(qv.y, wv.y, acc[1].y);
            acc[1].z = fmaf(qv.y, wv.z, acc[1].z);
            acc[1].w = fmaf(qv.y, wv.w, acc[1].w);
        }
    }

    *reinterpret_cast<float4*>(wq + (size_t)(r0 + 2 * tr + 0) * FF + f0 + 4 * tf) = acc[0];
    *reinterpret_cast<float4*>(wq + (size_t)(r0 + 2 * tr + 1) * FF + f0 + 4 * tf) = acc[1];
}

// ---------------- kernel 2: attention, 1024 threads = 16 waves x 4 t-rows (R9 best, verbatim) ----------------
__global__ __launch_bounds__(1024, 8) void attn_kernel4(const float* __restrict__ x,
                                                        const float* __restrict__ wq,
                                                        float* __restrict__ out) {
    const int tid  = threadIdx.x;
    const int lane = tid & 63;
    const int w    = tid >> 6;        // wave 0..15, owns t = 4w .. 4w+3
    const int row  = blockIdx.x;
    const float* xt = x + (size_t)row * (TT * FF);

    __shared__ float sc[TT];
    __shared__ float mbuf[16];
    __shared__ float lbuf[16];
    __shared__ float part[16][FF];

    float4 wqv = *reinterpret_cast<const float4*>(wq + (size_t)row * FF + 4 * lane);

    float4 xv[4];
#pragma unroll
    for (int j = 0; j < 4; ++j)
        xv[j] = ntload4(xt + (size_t)(w * 4 + j) * FF + 4 * lane);

    float p[4];
#pragma unroll
    for (int j = 0; j < 4; ++j)
        p[j] = xv[j].x * wqv.x + xv[j].y * wqv.y + xv[j].z * wqv.z + xv[j].w * wqv.w;

    const bool b5 = (lane & 32) != 0;
    const bool b4 = (lane & 16) != 0;

    float s2[2];
#pragma unroll
    for (int j = 0; j < 2; ++j) {
        float send = b5 ? p[j] : p[j + 2];
        float recv = __shfl_xor(send, 32, 64);
        s2[j] = (b5 ? p[j + 2] : p[j]) + recv;      // row = 2*b5 + j
    }
    float y;
    {
        float send = b4 ? s2[0] : s2[1];
        float recv = __shfl_xor(send, 16, 64);
        y = (b4 ? s2[1] : s2[0]) + recv;            // row = lane>>4
    }
    y += __shfl_xor(y, 8, 64);
    y += __shfl_xor(y, 4, 64);
    y += __shfl_xor(y, 2, 64);
    y += __shfl_xor(y, 1, 64);                      // full score of row lane>>4

    float mw = y;
    mw = fmaxf(mw, __shfl_xor(mw, 16, 64));
    mw = fmaxf(mw, __shfl_xor(mw, 32, 64));

    if ((lane & 15) == 0) sc[w * 4 + (lane >> 4)] = y;
    if (lane == 0) mbuf[w] = mw;
    __syncthreads();

    float m = mbuf[0];
#pragma unroll
    for (int i = 1; i < 16; ++i) m = fmaxf(m, mbuf[i]);

    float wt[4];
    float lw = 0.f;
#pragma unroll
    for (int j = 0; j < 4; ++j) {
        wt[j] = __expf(sc[w * 4 + j] - m);
        lw += wt[j];
    }

    float4 acc = make_float4(0.f, 0.f, 0.f, 0.f);
#pragma unroll
    for (int j = 0; j < 4; ++j) {
        acc.x += wt[j] * xv[j].x;
        acc.y += wt[j] * xv[j].y;
        acc.z += wt[j] * xv[j].z;
        acc.w += wt[j] * xv[j].w;
    }
    *reinterpret_cast<float4*>(&part[w][4 * lane]) = acc;
    if (lane == 0) lbuf[w] = lw;
    __syncthreads();

    if (tid < FF) {
        float l = 0.f;
#pragma unroll
        for (int i = 0; i < 16; ++i) l += lbuf[i];
        float v = 0.f;
#pragma unroll
        for (int i = 0; i < 16; ++i) v += part[i][tid];
        __builtin_nontemporal_store(v / l, out + (size_t)row * FF + tid);
    }
}

// ---------------- fallback: fully fused (only if ws too small) ----------------
__device__ __forceinline__ void attn_row_fb(const float* __restrict__ xt,
                                            float4 wqv,
                                            float* __restrict__ out_row,
                                            int tid) {
    const int lane = tid & 63;
    const int w    = tid >> 6;

    __shared__ float sc[TT];
    __shared__ float part[4][FF];

    float4 xv[16];
#pragma unroll
    for (int j = 0; j < 16; ++j)
        xv[j] = *reinterpret_cast<const float4*>(xt + (size_t)(w * 16 + j) * FF + 4 * lane);

#pragma unroll
    for (int j = 0; j < 16; ++j) {
        float s = xv[j].x * wqv.x + xv[j].y * wqv.y + xv[j].z * wqv.z + xv[j].w * wqv.w;
#pragma unroll
        for (int off = 32; off > 0; off >>= 1)
            s += __shfl_xor(s, off, 64);
        if (lane == 0) sc[w * 16 + j] = s;
    }
    __syncthreads();

    float m = -INFINITY;
#pragma unroll
    for (int t = 0; t < TT; ++t) m = fmaxf(m, sc[t]);
    float l = 0.f;
#pragma unroll
    for (int t = 0; t < TT; ++t) l += __expf(sc[t] - m);

    float4 acc = make_float4(0.f, 0.f, 0.f, 0.f);
#pragma unroll
    for (int j = 0; j < 16; ++j) {
        float wt = __expf(sc[w * 16 + j] - m);
        acc.x += wt * xv[j].x;
        acc.y += wt * xv[j].y;
        acc.z += wt * xv[j].z;
        acc.w += wt * xv[j].w;
    }
    *reinterpret_cast<float4*>(&part[w][4 * lane]) = acc;
    __syncthreads();

    float v = part[0][tid] + part[1][tid] + part[2][tid] + part[3][tid];
    out_row[tid] = v / l;
}

__global__ __launch_bounds__(256) void fused_kernel(const float* __restrict__ x,
                                                    const float* __restrict__ W,
                                                    float* __restrict__ out) {
    const int row = blockIdx.x;
    const int tid = threadIdx.x;
    const int lane = tid & 63;
    const float* xt = x + (size_t)row * (TT * FF);

    __shared__ float q[FF];
    __shared__ float wqs[FF];
    if (tid < 64) {
        float4 v = *reinterpret_cast<const float4*>(xt + (size_t)(TT - 1) * FF + tid * 4);
        *reinterpret_cast<float4*>(&q[tid * 4]) = v;
    }
    __syncthreads();

    float a = 0.f;
    const float* wrow = W + (size_t)tid * FF;
    for (int d0 = 0; d0 < FF; d0 += 4) {
        float4 wv = *reinterpret_cast<const float4*>(wrow + d0);
        float4 qv = *reinterpret_cast<const float4*>(&q[d0]);
        a += wv.x * qv.x + wv.y * qv.y + wv.z * qv.z + wv.w * qv.w;
    }
    wqs[tid] = a;
    __syncthreads();

    float4 wqv = *reinterpret_cast<const float4*>(&wqs[4 * lane]);
    attn_row_fb(xt, wqv, out + (size_t)row * FF, tid);
}

extern "C" void kernel_launch(void* const* d_in, const int* in_sizes, int n_in,
                              void* d_out, int out_size, void* d_ws, size_t ws_size,
                              hipStream_t stream) {
    (void)n_in; (void)out_size;
    const float* x = (const float*)d_in[0];
    const float* W = (const float*)d_in[1];
    float* out = (float*)d_out;

    const int rows = in_sizes[0] / (TT * FF);   // 8192
    const size_t wq_bytes = (size_t)rows * FF * sizeof(float);

    if (ws_size >= wq_bytes) {
        float* wq = (float*)d_ws;
        wq_gemm<<<(rows / BM) * 4, 256, 0, stream>>>(x, W, wq);
        attn_kernel4<<<rows, 1024, 0, stream>>>(x, wq, out);
    } else {
        fused_kernel<<<rows, 256, 0, stream>>>(x, W, out);
    }
}